// Round 8
// baseline (179.126 us; speedup 1.0000x reference)
//
#include <hip/hip_runtime.h>
#include <math.h>

// ---------------------------------------------------------------------------
// Deep4Net via bf16 MFMA 32x32x16 (fp32 accum). conv1+conv2 fused
// algebraically; pool(elu)=elu(pool). Each K=10 conv = 10 accumulated GEMMs:
//   out[o][t] += sum_i wk[k][o][i] * xT[t+k][i]
// A-frag: wk[k][o=mt*32+(lane&31)][i=kb*16+(lane>>5)*8 ..+7]  (global 16B)
// B-frag: xs[t=nt*32+(lane&31)+k ][i=kb*16+(lane>>5)*8 ..+7]  (ds_read_b128)
// C/D:    col=lane&31 (t), row=(reg&3)+8*(reg>>2)+4*(lane>>5) (o)
// 32x32x16 gives 2x FLOP per 16B fragment vs 16x16x32 -> LDS-read traffic
// halves (was the main-loop bottleneck). conv5 fuses the routed head: feats
// never leave LDS.
//
// Workspace: float region then short(bf16) region.
#define F_BC   0         // 32   combined bias (padded)
#define F_B2   32        // 64
#define F_B3   96        // 128
#define F_B4   224       // 224
#define SHORT_BASE 717696  // short index of bf16 region
#define WK12   0         // [10][32][32]
#define WK3    10240     // [10][64][32]
#define WK4    30720     // [10][128][64]
#define WK5    112640    // [10][224][128]
#define P1T    399360    // [256][330][32]
#define P2T    3102720   // [256][107][64]
#define P3T    4855808   // [256][32][128]
// ---------------------------------------------------------------------------

typedef __attribute__((ext_vector_type(8))) short short8;
typedef __attribute__((ext_vector_type(16))) float f32x16;

__device__ __forceinline__ short f2bf(float f) {
    union { float f; unsigned u; } v; v.f = f;
    unsigned r = v.u + 0x7FFF + ((v.u >> 16) & 1);
    return (short)(r >> 16);
}

// ---- K0: weight prep (combine conv1/2, transpose+pad all to bf16) ---------
__global__ __launch_bounds__(256) void k_prep2(
    const float* __restrict__ wt, const float* __restrict__ bt,
    const float* __restrict__ wsp, const float* __restrict__ bsp,
    const float* __restrict__ w2, const float* __restrict__ b2,
    const float* __restrict__ w3, const float* __restrict__ b3,
    const float* __restrict__ w4, const float* __restrict__ b4,
    float* __restrict__ wsf, short* __restrict__ wss) {
    int idx = blockIdx.x * 256 + threadIdx.x;
    if (idx < 448) {                           // padded biases (f32)
        float v = 0.f;
        if (idx < 32) {
            int o = idx;
            if (o < 25) {
                v = bsp[o];
                for (int i = 0; i < 25; ++i) {
                    float rs = 0.f;
                    for (int c = 0; c < 22; ++c) rs += wsp[(o * 25 + i) * 22 + c];
                    v += bt[i] * rs;
                }
            }
        } else if (idx < 96)  { int o = idx - 32;  v = (o < 50)  ? b2[o] : 0.f; }
        else if (idx < 224)   { int o = idx - 96;  v = (o < 100) ? b3[o] : 0.f; }
        else                  { int o = idx - 224; v = (o < 200) ? b4[o] : 0.f; }
        wsf[idx] = v;
        return;
    }
    int j = idx - 448;
    if (j < 10240) {                           // wk12 [k][32][32] (combined)
        int k = j / 1024, o = (j / 32) % 32, i = j % 32;
        float v = 0.f;
        if (o < 25 && i < 22)
            for (int q = 0; q < 25; ++q) v += wt[q * 10 + k] * wsp[(o * 25 + q) * 22 + i];
        wss[WK12 + j] = f2bf(v);
        return;
    }
    j -= 10240;
    if (j < 20480) {                           // wk3 [k][64][32]
        int k = j / 2048, o = (j / 32) % 64, i = j % 32;
        float v = (o < 50 && i < 25) ? w2[(o * 25 + i) * 10 + k] : 0.f;
        wss[WK3 + j] = f2bf(v);
        return;
    }
    j -= 20480;
    if (j < 81920) {                           // wk4 [k][128][64]
        int k = j / 8192, o = (j / 64) % 128, i = j % 64;
        float v = (o < 100 && i < 50) ? w3[(o * 50 + i) * 10 + k] : 0.f;
        wss[WK4 + j] = f2bf(v);
        return;
    }
    j -= 81920;
    if (j < 286720) {                          // wk5 [k][224][128]
        int k = j / 28672, o = (j / 128) % 224, i = j % 128;
        float v = (o < 200 && i < 100) ? w4[(o * 100 + i) * 10 + k] : 0.f;
        wss[WK5 + j] = f2bf(v);
    }
}

// ---- generic 32x32x16 MFMA conv+pool+ELU layer (optionally fused head) ----
// block = MTB*NTILES waves; wave w -> (m-tile w/NTILES, n-tile w%NTILES)
// grid: idx = b + 256*(nc + NC*mc)
template<int OPAD, int IPAD, int MTB, int NTILES, int NCHUNK, bool F32IN, bool FUSE>
__global__ __launch_bounds__(MTB * NTILES * 64) void k_cmfma(
    const short* __restrict__ wk, const float* __restrict__ bias,
    const short* __restrict__ xinT, const float* __restrict__ xf32,
    short* __restrict__ outT, int NC, int TIN, int NPtot,
    const float* __restrict__ hW, const float* __restrict__ hB,
    const int* __restrict__ sid, float* __restrict__ out) {
    constexpr int BS = MTB * NTILES * 64;
    constexpr int MSPAN = MTB * 32;
    constexpr int ROWS = NTILES * 32 + 9;
    constexpr int XSTR = IPAD + 4;      // row stride: <=2-way bank aliasing
    constexpr int SSTR = MSPAN + 1;     // odd stride: conflict-free sc
    constexpr int NCT = NTILES * 32;
    constexpr int KB = IPAD / 16;
    __shared__ short xs[ROWS * XSTR];
    __shared__ float sc[NCT * SSTR];
    __shared__ float feats[FUSE ? 1408 : 4];

    int idx = blockIdx.x;
    int b = idx % 256;
    int nc = (idx / 256) % NC;
    int mc = idx / (256 * NC);
    int t0 = nc * NCHUNK;
    int tid = threadIdx.x;

    // ---- stage input tile into LDS (bf16, time-major) ----
    if constexpr (F32IN) {
        const float* xb = xf32 + b * 22000;
        for (int i = tid; i < 32 * 128; i += BS) {
            int c = i >> 7, r = i & 127;
            if (r < ROWS) {
                short v = 0;
                if (c < 22) {
                    int t = t0 + r; if (t > TIN - 1) t = TIN - 1;
                    v = f2bf(xb[c * 1000 + t]);
                }
                xs[r * XSTR + c] = v;
            }
        }
    } else {
        const short* xb = xinT + (size_t)b * TIN * IPAD;
        constexpr int V = IPAD / 8;
        for (int i = tid; i < ROWS * V; i += BS) {
            int r = i / V, vv = i - r * V;
            int t = t0 + r; if (t >= TIN) t = TIN - 1;   // clamp; extras discarded
            *(short8*)(xs + r * XSTR + vv * 8) =
                *(const short8*)(xb + (size_t)t * IPAD + vv * 8);
        }
    }
    __syncthreads();

    int w = tid >> 6, lane = tid & 63, l31 = lane & 31, half = lane >> 5;
    int mtl = w / NTILES, nt = w % NTILES;
    int orow = mc * MSPAN + mtl * 32 + l31;

    f32x16 acc = {};
    const short* wbase = wk + (size_t)orow * IPAD + half * 8;
#pragma unroll 2
    for (int k = 0; k < 10; ++k) {
#pragma unroll
        for (int kb = 0; kb < KB; ++kb) {
            short8 a = *(const short8*)(wbase + (size_t)k * OPAD * IPAD + kb * 16);
            short8 bf = *(const short8*)(xs + (nt * 32 + l31 + k) * XSTR +
                                         kb * 16 + half * 8);
            acc = __builtin_amdgcn_mfma_f32_32x32x16_bf16(a, bf, acc, 0, 0, 0);
        }
    }

    // ---- C frags -> LDS f32 scratch, transposed: sc[col][o_local] ----
    {
        float* scl = sc + (nt * 32 + l31) * SSTR + mtl * 32 + 4 * half;
#pragma unroll
        for (int reg = 0; reg < 16; ++reg) {
            int row = (reg & 3) + 8 * (reg >> 2);
            scl[row] = acc[reg];
        }
    }
    __syncthreads();

    // ---- pool3 + bias + ELU + store ----
    constexpr int PC = NCHUNK / 3;
    int pc0 = nc * PC;
    for (int i = tid; i < PC * MSPAN; i += BS) {
        int tp = i / MSPAN, ol = i - tp * MSPAN;
        if (pc0 + tp < NPtot) {
            float s0 = sc[(tp * 3 + 0) * SSTR + ol];
            float s1 = sc[(tp * 3 + 1) * SSTR + ol];
            float s2 = sc[(tp * 3 + 2) * SSTR + ol];
            float m = fmaxf(fmaxf(s0, s1), s2) + bias[mc * MSPAN + ol];
            float e = m > 0.f ? m : __expf(m) - 1.f;
            if constexpr (FUSE) {
                if (ol < 200) feats[ol * 7 + tp] = e;
            } else {
                outT[(size_t)b * NPtot * OPAD + (size_t)(pc0 + tp) * OPAD +
                     mc * MSPAN + ol] = f2bf(e);
            }
        }
    }

    if constexpr (FUSE) {
        __syncthreads();
        if (w < 4) {
            int sidb = sid[b];
            const float* wrow = hW + (sidb * 4 + w) * 1400;
            float a = 0.f;
            for (int f = lane; f < 1400; f += 64) a += wrow[f] * feats[f];
#pragma unroll
            for (int off = 32; off; off >>= 1) a += __shfl_down(a, off);
            if (lane == 0) out[b * 4 + w] = a + hB[sidb * 4 + w];
        }
    }
}

extern "C" void kernel_launch(void* const* d_in, const int* in_sizes, int n_in,
                              void* d_out, int out_size, void* d_ws, size_t ws_size,
                              hipStream_t stream) {
    const float* x   = (const float*)d_in[0];
    const int*   sid = (const int*)d_in[1];
    const float* wt  = (const float*)d_in[2];
    const float* bt  = (const float*)d_in[3];
    const float* wsp = (const float*)d_in[4];
    const float* bsp = (const float*)d_in[5];
    const float* w2  = (const float*)d_in[6];
    const float* b2  = (const float*)d_in[7];
    const float* w3  = (const float*)d_in[8];
    const float* b3  = (const float*)d_in[9];
    const float* w4  = (const float*)d_in[10];
    const float* b4  = (const float*)d_in[11];
    const float* hW  = (const float*)d_in[12];
    const float* hB  = (const float*)d_in[13];
    float* out = (float*)d_out;
    float* wsf = (float*)d_ws;
    short* wss = (short*)d_ws + SHORT_BASE;

    k_prep2<<<1562, 256, 0, stream>>>(wt, bt, wsp, bsp, w2, b2, w3, b3, w4, b4,
                                      wsf, wss);
    // conv12: M=32(25), 330 pooled; 11 n-chunks of 96; 3 waves
    k_cmfma<32, 32, 1, 3, 96, true, false><<<256 * 11, 192, 0, stream>>>(
        wss + WK12, wsf + F_BC, nullptr, x, wss + P1T, 11, 1000, 330,
        nullptr, nullptr, nullptr, nullptr);
    // conv3: M=64(50), 107 pooled; 4 n-chunks of 96; 6 waves (2m x 3n)
    k_cmfma<64, 32, 2, 3, 96, false, false><<<256 * 4, 384, 0, stream>>>(
        wss + WK3, wsf + F_B2, wss + P1T, nullptr, wss + P2T, 4, 330, 107,
        nullptr, nullptr, nullptr, nullptr);
    // conv4: M=128(100) in 2 mc, 32 pooled; 1 n-chunk of 96; 6 waves
    k_cmfma<128, 64, 2, 3, 96, false, false><<<512, 384, 0, stream>>>(
        wss + WK4, wsf + F_B3, wss + P2T, nullptr, wss + P3T, 1, 107, 32,
        nullptr, nullptr, nullptr, nullptr);
    // conv5 + head: M=224(200), 7 pooled; 7 waves (7m x 1n); feats in LDS
    k_cmfma<224, 128, 7, 1, 21, false, true><<<256, 448, 0, stream>>>(
        wss + WK5, wsf + F_B4, wss + P3T, nullptr, nullptr, 1, 32, 7,
        hW, hB, sid, out);
}